// Round 2
// baseline (851.077 us; speedup 1.0000x reference)
//
#include <hip/hip_runtime.h>
#include <math.h>

// Problem geometry
// B=4, L=4096, H=16, NBk=64, D=1024, HID=128, NS=1024, TOKENS=16384
// Chunking: 128 tokens/chunk -> 32 chunks per sequence of 4096.
// out layout: [theta_hat 16777216 | Pi 1024 | K 16777216 | R 16777216]
static constexpr size_t OUT_THETA = 0;
static constexpr size_t OUT_PI    = 16777216;
static constexpr size_t OUT_K     = 16778240;
static constexpr size_t OUT_R     = 33555456;

#define PI_F     3.14159265358979323846f
#define INV2PI_F 0.15915494309189535f
#define PI2_HI   6.28318548202514648f   // fp32(2*pi)
#define PI2_LO  -1.7484556e-7f          // 2*pi - PI2_HI

// ---------------------------------------------------------------------------
// K1: H = gelu_exact(X @ W1 + b1) for both heads.
// Tile 128 tokens x 128 cols (one full head), 256 threads, 8x8 microtile.
// grid (128 token tiles, 2 heads). Register-prefetch software pipeline.
// LDS ratio: 64 B per 64 FMA/thread/kk = 1.0 B/FMA (balanced vs 128 B/cyc).
// ---------------------------------------------------------------------------
__global__ __launch_bounds__(256) void k_gemm1(
    const float* __restrict__ X,
    const float* __restrict__ Wr1, const float* __restrict__ br1,
    const float* __restrict__ Wm1, const float* __restrict__ bm1,
    float* __restrict__ Hout)
{
    __shared__ float As[16][132];   // [k][m] padded: +132 -> 2-way max on stores
    __shared__ float Bs[16][132];   // [k][n]
    const int tt = blockIdx.x;
    const int nt = blockIdx.y;                 // 0 = r head, 1 = m head
    const float* __restrict__ W    = (nt == 0) ? Wr1 : Wm1;
    const float* __restrict__ bias = (nt == 0) ? br1 : bm1;
    const int m0  = tt * 128;
    const int tid = threadIdx.x;
    const int tm = tid >> 4, tn = tid & 15;    // micro: rows tm*8+i, cols tn*8+j
    const int ra = tid >> 1, ka = (tid & 1) * 8;       // A loader: 2 f4 along k
    const int rb = tid >> 5, cb = (tid & 31) * 4;      // B loader: 2 f4 rows rb, rb+8

    float4 a0, a1, b0, b1;
    auto loadT = [&](int k0) {
        const float* xp = X + (size_t)(m0 + ra) * 1024 + k0 + ka;
        a0 = *(const float4*)(xp);
        a1 = *(const float4*)(xp + 4);
        b0 = *(const float4*)(W + (size_t)(k0 + rb) * 128 + cb);
        b1 = *(const float4*)(W + (size_t)(k0 + 8 + rb) * 128 + cb);
    };

    float acc[8][8] = {};
    loadT(0);
    for (int k0 = 0; k0 < 1024; k0 += 16) {
        __syncthreads();
        const float* ap = (const float*)&a0;
#pragma unroll
        for (int c = 0; c < 4; ++c) As[ka + c][ra] = ap[c];
        ap = (const float*)&a1;
#pragma unroll
        for (int c = 0; c < 4; ++c) As[ka + 4 + c][ra] = ap[c];
        *(float4*)&Bs[rb][cb]     = b0;
        *(float4*)&Bs[rb + 8][cb] = b1;
        __syncthreads();
        if (k0 + 16 < 1024) loadT(k0 + 16);   // prefetch overlaps compute below
#pragma unroll
        for (int kk = 0; kk < 16; ++kk) {
            float4 av0 = *(const float4*)&As[kk][tm * 8];
            float4 av1 = *(const float4*)&As[kk][tm * 8 + 4];
            float4 bv0 = *(const float4*)&Bs[kk][tn * 8];
            float4 bv1 = *(const float4*)&Bs[kk][tn * 8 + 4];
            const float* a = (const float*)&av0;
            const float* b = (const float*)&bv0;
#pragma unroll
            for (int i = 0; i < 8; ++i) {
                float ai = (i < 4) ? a[i] : ((const float*)&av1)[i - 4];
#pragma unroll
                for (int j = 0; j < 8; ++j) {
                    float bj = (j < 4) ? b[j] : ((const float*)&bv1)[j - 4];
                    acc[i][j] = fmaf(ai, bj, acc[i][j]);
                }
            }
        }
    }
    float bb[8];
#pragma unroll
    for (int j = 0; j < 8; ++j) bb[j] = bias[tn * 8 + j];
#pragma unroll
    for (int i = 0; i < 8; ++i) {
        float4 h0, h1;
#pragma unroll
        for (int j = 0; j < 8; ++j) {
            float x = acc[i][j] + bb[j];
            float g = 0.5f * x * (1.0f + erff(x * 0.70710678118654752f));
            if (j < 4) ((float*)&h0)[j] = g; else ((float*)&h1)[j - 4] = g;
        }
        float* hp = Hout + (size_t)(m0 + tm * 8 + i) * 256 + nt * 128 + tn * 8;
        *(float4*)(hp)     = h0;
        *(float4*)(hp + 4) = h1;
    }
}

// ---------------------------------------------------------------------------
// K2: second linear (both heads, K=128) + elementwise tail + chunk aggregates.
// Tile 128 tokens (one chunk) x 64 cols, 256 threads, 8x4 microtile per head.
// Thread rows are 8 CONTIGUOUS tokens -> affine scan segment composed in
// registers; 16 segments combined via small LDS. No atan2/sin/cos: exact wrap.
// ---------------------------------------------------------------------------
__global__ __launch_bounds__(256) void k_head2(
    const float* __restrict__ Hin,
    const float* __restrict__ Wr2, const float* __restrict__ br2,
    const float* __restrict__ Wm2, const float* __restrict__ bm2,
    const float* __restrict__ log_Pi, const float* __restrict__ theta,
    float* __restrict__ out, float* __restrict__ Aws, float* __restrict__ Uws)
{
    __shared__ union {
        struct { float Ar[16][132]; float Am[16][132]; float Br[16][68]; float Bm[16][68]; } g;
        struct { float cA[64][17]; float cU[64][17]; } c;
    } sm;
    const int tt = blockIdx.x;           // chunk index 0..127  (b = tt>>5, c = tt&31)
    const int jt = blockIdx.y;           // 0..15
    const int m0 = tt * 128, n0 = jt * 64;
    const int tid = threadIdx.x;
    const int tm = tid >> 4, tn = tid & 15;        // rows tm*8+i, cols tn*4+j
    const int ra = tid >> 1, ka = (tid & 1) * 8;   // A loader
    const int rb = tid >> 4, cbl = (tid & 15) * 4; // B loader

    float4 ar0, ar1, am0, am1, brv, bmv;
    auto loadT = [&](int k0) {
        const float* hp = Hin + (size_t)(m0 + ra) * 256 + k0 + ka;
        ar0 = *(const float4*)(hp);
        ar1 = *(const float4*)(hp + 4);
        am0 = *(const float4*)(hp + 128);
        am1 = *(const float4*)(hp + 132);
        brv = *(const float4*)(Wr2 + (size_t)(k0 + rb) * 1024 + n0 + cbl);
        bmv = *(const float4*)(Wm2 + (size_t)(k0 + rb) * 1024 + n0 + cbl);
    };

    float accr[8][4] = {}, accm[8][4] = {};
    loadT(0);
    for (int k0 = 0; k0 < 128; k0 += 16) {
        __syncthreads();
        {
            const float* p = (const float*)&ar0;
#pragma unroll
            for (int c = 0; c < 4; ++c) sm.g.Ar[ka + c][ra] = p[c];
            p = (const float*)&ar1;
#pragma unroll
            for (int c = 0; c < 4; ++c) sm.g.Ar[ka + 4 + c][ra] = p[c];
            p = (const float*)&am0;
#pragma unroll
            for (int c = 0; c < 4; ++c) sm.g.Am[ka + c][ra] = p[c];
            p = (const float*)&am1;
#pragma unroll
            for (int c = 0; c < 4; ++c) sm.g.Am[ka + 4 + c][ra] = p[c];
            *(float4*)&sm.g.Br[rb][cbl] = brv;
            *(float4*)&sm.g.Bm[rb][cbl] = bmv;
        }
        __syncthreads();
        if (k0 + 16 < 128) loadT(k0 + 16);
#pragma unroll
        for (int kk = 0; kk < 16; ++kk) {
            float4 avr0 = *(const float4*)&sm.g.Ar[kk][tm * 8];
            float4 avr1 = *(const float4*)&sm.g.Ar[kk][tm * 8 + 4];
            float4 avm0 = *(const float4*)&sm.g.Am[kk][tm * 8];
            float4 avm1 = *(const float4*)&sm.g.Am[kk][tm * 8 + 4];
            float4 bvr  = *(const float4*)&sm.g.Br[kk][tn * 4];
            float4 bvm  = *(const float4*)&sm.g.Bm[kk][tn * 4];
#pragma unroll
            for (int i = 0; i < 8; ++i) {
                float air = (i < 4) ? ((const float*)&avr0)[i] : ((const float*)&avr1)[i - 4];
                float aim = (i < 4) ? ((const float*)&avm0)[i] : ((const float*)&avm1)[i - 4];
#pragma unroll
                for (int j = 0; j < 4; ++j) {
                    accr[i][j] = fmaf(air, ((const float*)&bvr)[j], accr[i][j]);
                    accm[i][j] = fmaf(aim, ((const float*)&bvm)[j], accm[i][j]);
                }
            }
        }
    }

    float Pis[4], b2r[4], b2m[4];
#pragma unroll
    for (int j = 0; j < 4; ++j) {
        Pis[j] = expf(log_Pi[n0 + tn * 4 + j]);
        b2r[j] = br2[n0 + tn * 4 + j];
        b2m[j] = bm2[n0 + tn * 4 + j];
    }
    float aP[4] = {1.f, 1.f, 1.f, 1.f}, uE[4] = {};
#pragma unroll
    for (int i = 0; i < 8; ++i) {
        const size_t idx = (size_t)(m0 + tm * 8 + i) * 1024 + n0 + tn * 4;
        float4 th4 = *(const float4*)(theta + idx);
        float4 Kv, Rv, Uv;
#pragma unroll
        for (int j = 0; j < 4; ++j) {
            float lr = fminf(fmaxf(accr[i][j] + b2r[j], -5.0f), 5.0f);
            float R  = expf(lr);
            float Kg = __fdividef(Pis[j], fmaxf(Pis[j] + R, 1e-8f));
            float z  = PI_F * tanhf(accm[i][j] + b2m[j]);
            float d  = z - ((const float*)&th4)[j];
            float n  = rintf(d * INV2PI_F);
            float nu = fmaf(-n, PI2_HI, d);
            nu       = fmaf(-n, PI2_LO, nu);        // wrapped innovation
            float u  = Kg * nu;
            float al = 1.0f - Kg;
            uE[j] = fmaf(al, uE[j], u);             // token-ascending fold
            aP[j] *= al;
            ((float*)&Kv)[j] = Kg; ((float*)&Rv)[j] = R; ((float*)&Uv)[j] = u;
        }
        *(float4*)(out + OUT_K + idx)     = Kv;
        *(float4*)(out + OUT_R + idx)     = Rv;
        *(float4*)(out + OUT_THETA + idx) = Uv;     // u stashed in theta slot
    }
    __syncthreads();   // all GEMM LDS reads done; union reused for combine
#pragma unroll
    for (int j = 0; j < 4; ++j) {
        sm.c.cA[tn * 4 + j][tm] = aP[j];
        sm.c.cU[tn * 4 + j][tm] = uE[j];
    }
    __syncthreads();
    if (tid < 64) {       // compose 16 segments (token order) -> chunk aggregate
        float A = 1.0f, U = 0.0f;
#pragma unroll
        for (int s = 0; s < 16; ++s) {
            float a = sm.c.cA[tid][s];
            float u = sm.c.cU[tid][s];
            U = fmaf(a, U, u);
            A *= a;
        }
        Aws[(size_t)tt * 1024 + n0 + tid] = A;
        Uws[(size_t)tt * 1024 + n0 + tid] = U;
    }
}

// ---------------------------------------------------------------------------
// K3: serial scan over the 32 chunk aggregates per sequence -> chunk carries.
// ---------------------------------------------------------------------------
__global__ __launch_bounds__(256) void k_carry(
    const float* __restrict__ Aws, const float* __restrict__ Uws, float* __restrict__ Cws)
{
    const int b = blockIdx.x >> 2;
    const int j = (blockIdx.x & 3) * 256 + threadIdx.x;
    float carry = 0.0f;
    for (int c = 0; c < 32; ++c) {
        const size_t off = (size_t)(b * 32 + c) * 1024 + j;
        float a = Aws[off], u = Uws[off];
        Cws[off] = carry;               // carry entering chunk c
        carry = fmaf(a, carry, u);
    }
}

// ---------------------------------------------------------------------------
// K4: apply — rescan each 128-token chunk seeded with its carry.
// theta_hat = theta + d, overwriting the stashed u in place.
// ---------------------------------------------------------------------------
__global__ __launch_bounds__(256) void k_apply(
    const float* __restrict__ theta, const float* __restrict__ Cws, float* __restrict__ out)
{
    const int bid = blockIdx.x;          // (b<<7) | (c<<2) | jg
    const int jg = bid & 3;
    const int c  = (bid >> 2) & 31;
    const int b  = bid >> 7;
    const int j  = jg * 256 + threadIdx.x;
    float d = Cws[(size_t)(b * 32 + c) * 1024 + j];
    size_t idx = (size_t)(b * 4096 + c * 128) * 1024 + j;
    const float* __restrict__ Kbase = out + OUT_K;
#pragma unroll 4
    for (int i = 0; i < 128; ++i) {
        float Kg = Kbase[idx];
        float u  = out[idx];
        d = fmaf(1.0f - Kg, d, u);
        out[idx] = theta[idx] + d;
        idx += 1024;
    }
}

__global__ void k_pi(const float* __restrict__ log_Pi, float* __restrict__ out)
{
    int j = blockIdx.x * 256 + threadIdx.x;
    if (j < 1024) out[OUT_PI + j] = expf(log_Pi[j]);
}

extern "C" void kernel_launch(void* const* d_in, const int* in_sizes, int n_in,
                              void* d_out, int out_size, void* d_ws, size_t ws_size,
                              hipStream_t stream)
{
    const float* theta = (const float*)d_in[0];
    const float* x     = (const float*)d_in[1];
    const float* logPi = (const float*)d_in[2];
    const float* Wr1   = (const float*)d_in[3];
    const float* br1   = (const float*)d_in[4];
    const float* Wr2   = (const float*)d_in[5];
    const float* br2   = (const float*)d_in[6];
    const float* Wm1   = (const float*)d_in[7];
    const float* bm1   = (const float*)d_in[8];
    const float* Wm2   = (const float*)d_in[9];
    const float* bm2   = (const float*)d_in[10];
    float* out = (float*)d_out;

    float* Hws = (float*)d_ws;                       // 16384*256 floats
    float* Aws = Hws + (size_t)16384 * 256;          // 131072 floats
    float* Uws = Aws + 131072;
    float* Cws = Uws + 131072;

    k_gemm1<<<dim3(128, 2), 256, 0, stream>>>(x, Wr1, br1, Wm1, bm1, Hws);
    k_pi<<<4, 256, 0, stream>>>(logPi, out);
    k_head2<<<dim3(128, 16), 256, 0, stream>>>(Hws, Wr2, br2, Wm2, bm2, logPi, theta, out, Aws, Uws);
    k_carry<<<16, 256, 0, stream>>>(Aws, Uws, Cws);
    k_apply<<<512, 256, 0, stream>>>(theta, Cws, out);
}

// Round 3
// 604.130 us; speedup vs baseline: 1.4088x; 1.4088x over previous
//
#include <hip/hip_runtime.h>
#include <math.h>

// Problem geometry
// B=4, L=4096, H=16, NB=64, D=1024, HID=128, NS=1024, TOKENS=16384
// Chunking: 64 tokens/chunk -> 64 chunks per sequence of 4096, 256 chunks total.
// out layout: [theta_hat 16777216 | Pi 1024 | K 16777216 | R 16777216]
static constexpr size_t OUT_THETA = 0;
static constexpr size_t OUT_PI    = 16777216;
static constexpr size_t OUT_K     = 16778240;
static constexpr size_t OUT_R     = 33555456;

#define PI_F     3.14159265358979323846f
#define INV2PI_F 0.15915494309189535f
#define PI2_HI   6.28318548202514648f   // fp32(2*pi)
#define PI2_LO  -1.7484556e-7f          // 2*pi - PI2_HI

// ---------------------------------------------------------------------------
// K1: H = gelu_exact(X @ W1 + b1), both heads.
// Tile 32 tokens x 128 cols, 256 threads, 4x4 microtile (acc=16) -> low VGPR,
// high TLP. grid (512 token tiles, 2 heads) = 1024 blocks (4/CU).
// A staged [k][row] (broadcast-friendly); LDS = 10.8 KB/block.
// ---------------------------------------------------------------------------
__global__ __launch_bounds__(256, 4) void k_gemm1(
    const float* __restrict__ X,
    const float* __restrict__ Wr1, const float* __restrict__ br1,
    const float* __restrict__ Wm1, const float* __restrict__ bm1,
    float* __restrict__ Hout)
{
    __shared__ float As[16][36];    // [k][row], 2.3 KB
    __shared__ float Bs[16][132];   // [k][col], 8.4 KB
    const int tt = blockIdx.x;
    const int nt = blockIdx.y;                  // 0 = r head, 1 = m head
    const float* __restrict__ W    = (nt == 0) ? Wr1 : Wm1;
    const float* __restrict__ bias = (nt == 0) ? br1 : bm1;
    const int m0  = tt * 32;
    const int tid = threadIdx.x;
    const int tn = tid & 31, tm = tid >> 5;     // rows tm*4+i, cols tn*4+j
    const int al_row = tid >> 2, al_k = (tid & 3) * 4;   // A loader (tid<128)
    const int bl_r = tid >> 4, bl_c = (tid & 15) * 4;    // B loader (all)

    float4 apf, bpf0, bpf1;
    auto loadT = [&](int k0) {
        if (tid < 128)
            apf = *(const float4*)(X + (size_t)(m0 + al_row) * 1024 + k0 + al_k);
        bpf0 = *(const float4*)(W + (size_t)(k0 + bl_r) * 128 + bl_c);
        bpf1 = *(const float4*)(W + (size_t)(k0 + bl_r) * 128 + bl_c + 64);
    };

    float acc[4][4] = {};
    loadT(0);
    for (int k0 = 0; k0 < 1024; k0 += 16) {
        __syncthreads();
        if (tid < 128) {
            const float* p = (const float*)&apf;
#pragma unroll
            for (int c = 0; c < 4; ++c) As[al_k + c][al_row] = p[c];
        }
        *(float4*)&Bs[bl_r][bl_c]      = bpf0;
        *(float4*)&Bs[bl_r][bl_c + 64] = bpf1;
        __syncthreads();
        if (k0 + 16 < 1024) loadT(k0 + 16);
#pragma unroll
        for (int kk = 0; kk < 16; ++kk) {
            float4 av = *(const float4*)&As[kk][tm * 4];
            float4 bv = *(const float4*)&Bs[kk][tn * 4];
#pragma unroll
            for (int i = 0; i < 4; ++i)
#pragma unroll
                for (int j = 0; j < 4; ++j)
                    acc[i][j] = fmaf(((const float*)&av)[i], ((const float*)&bv)[j], acc[i][j]);
        }
    }
    float bb[4];
#pragma unroll
    for (int j = 0; j < 4; ++j) bb[j] = bias[tn * 4 + j];
#pragma unroll
    for (int i = 0; i < 4; ++i) {
        float4 hv;
#pragma unroll
        for (int j = 0; j < 4; ++j) {
            float x = acc[i][j] + bb[j];
            ((float*)&hv)[j] = 0.5f * x * (1.0f + erff(x * 0.70710678118654752f));
        }
        *(float4*)(Hout + (size_t)(m0 + tm * 4 + i) * 256 + nt * 128 + tn * 4) = hv;
    }
}

// ---------------------------------------------------------------------------
// K2: second linear (both heads, K=128) + elementwise tail + chunk aggregates.
// Tile 64 tokens (one chunk) x 64 cols, 256 threads, 4x4 microtile per head
// (acc=32). grid (256 chunks, 16 jt) = 4096 blocks (16/CU). LDS 17.4 KB.
// Thread rows are 4 CONTIGUOUS tokens -> register scan fold, 16-segment
// LDS combine -> chunk aggregate (A = prod alpha, U = local scan end).
// ---------------------------------------------------------------------------
__global__ __launch_bounds__(256, 4) void k_head2(
    const float* __restrict__ Hin,
    const float* __restrict__ Wr2, const float* __restrict__ br2,
    const float* __restrict__ Wm2, const float* __restrict__ bm2,
    const float* __restrict__ log_Pi, const float* __restrict__ theta,
    float* __restrict__ out, float* __restrict__ Aws, float* __restrict__ Uws)
{
    __shared__ union {
        struct { float Ar[16][68]; float Am[16][68]; float Br[16][68]; float Bm[16][68]; } g;
        struct { float cA[64][17]; float cU[64][17]; } c;
    } sm;
    const int tt = blockIdx.x;            // chunk 0..255 (b = tt>>6, c = tt&63)
    const int jt = blockIdx.y;            // 0..15
    const int m0 = tt * 64, n0 = jt * 64;
    const int tid = threadIdx.x;
    const int tm = tid >> 4, tn = tid & 15;        // rows tm*4+i, cols tn*4+j
    const int ar_row = tid >> 2, ar_k = (tid & 3) * 4;   // A loader
    const int br_r = tid >> 4, br_c = (tid & 15) * 4;    // B loader

    float4 par, pam, pbr, pbm;
    auto loadT = [&](int k0) {
        const float* hp = Hin + (size_t)(m0 + ar_row) * 256 + k0 + ar_k;
        par = *(const float4*)(hp);
        pam = *(const float4*)(hp + 128);
        pbr = *(const float4*)(Wr2 + (size_t)(k0 + br_r) * 1024 + n0 + br_c);
        pbm = *(const float4*)(Wm2 + (size_t)(k0 + br_r) * 1024 + n0 + br_c);
    };

    float accr[4][4] = {}, accm[4][4] = {};
    loadT(0);
    for (int k0 = 0; k0 < 128; k0 += 16) {
        __syncthreads();
        {
            const float* p = (const float*)&par;
            const float* q = (const float*)&pam;
#pragma unroll
            for (int c = 0; c < 4; ++c) {
                sm.g.Ar[ar_k + c][ar_row] = p[c];
                sm.g.Am[ar_k + c][ar_row] = q[c];
            }
            *(float4*)&sm.g.Br[br_r][br_c] = pbr;
            *(float4*)&sm.g.Bm[br_r][br_c] = pbm;
        }
        __syncthreads();
        if (k0 + 16 < 128) loadT(k0 + 16);
#pragma unroll
        for (int kk = 0; kk < 16; ++kk) {
            float4 avr = *(const float4*)&sm.g.Ar[kk][tm * 4];
            float4 avm = *(const float4*)&sm.g.Am[kk][tm * 4];
            float4 bvr = *(const float4*)&sm.g.Br[kk][tn * 4];
            float4 bvm = *(const float4*)&sm.g.Bm[kk][tn * 4];
#pragma unroll
            for (int i = 0; i < 4; ++i)
#pragma unroll
                for (int j = 0; j < 4; ++j) {
                    accr[i][j] = fmaf(((const float*)&avr)[i], ((const float*)&bvr)[j], accr[i][j]);
                    accm[i][j] = fmaf(((const float*)&avm)[i], ((const float*)&bvm)[j], accm[i][j]);
                }
        }
    }

    float Pis[4], b2r[4], b2m[4];
#pragma unroll
    for (int j = 0; j < 4; ++j) {
        Pis[j] = expf(log_Pi[n0 + tn * 4 + j]);
        b2r[j] = br2[n0 + tn * 4 + j];
        b2m[j] = bm2[n0 + tn * 4 + j];
    }
    float aP[4] = {1.f, 1.f, 1.f, 1.f}, uE[4] = {};
#pragma unroll
    for (int i = 0; i < 4; ++i) {
        const size_t idx = (size_t)(m0 + tm * 4 + i) * 1024 + n0 + tn * 4;
        float4 th4 = *(const float4*)(theta + idx);
        float4 Kv, Rv, Uv;
#pragma unroll
        for (int j = 0; j < 4; ++j) {
            float lr = fminf(fmaxf(accr[i][j] + b2r[j], -5.0f), 5.0f);
            float R  = expf(lr);
            float Kg = __fdividef(Pis[j], fmaxf(Pis[j] + R, 1e-8f));
            float z  = PI_F * tanhf(accm[i][j] + b2m[j]);
            float d  = z - ((const float*)&th4)[j];
            float n  = rintf(d * INV2PI_F);
            float nu = fmaf(-n, PI2_HI, d);
            nu       = fmaf(-n, PI2_LO, nu);        // wrapped innovation
            float u  = Kg * nu;
            float al = 1.0f - Kg;
            uE[j] = fmaf(al, uE[j], u);             // token-ascending fold
            aP[j] *= al;
            ((float*)&Kv)[j] = Kg; ((float*)&Rv)[j] = R; ((float*)&Uv)[j] = u;
        }
        *(float4*)(out + OUT_K + idx)     = Kv;
        *(float4*)(out + OUT_R + idx)     = Rv;
        *(float4*)(out + OUT_THETA + idx) = Uv;     // u stashed in theta slot
    }
    __syncthreads();   // GEMM LDS reads done; union reused for combine
#pragma unroll
    for (int j = 0; j < 4; ++j) {
        sm.c.cA[tn * 4 + j][tm] = aP[j];
        sm.c.cU[tn * 4 + j][tm] = uE[j];
    }
    __syncthreads();
    if (tid < 64) {       // compose 16 segments (token order) -> chunk aggregate
        float A = 1.0f, U = 0.0f;
#pragma unroll
        for (int s = 0; s < 16; ++s) {
            float a = sm.c.cA[tid][s];
            float u = sm.c.cU[tid][s];
            U = fmaf(a, U, u);
            A *= a;
        }
        Aws[(size_t)tt * 1024 + n0 + tid] = A;
        Uws[(size_t)tt * 1024 + n0 + tid] = U;
    }
}

// ---------------------------------------------------------------------------
// K3: serial scan over 64 chunk aggregates per sequence -> chunk carries.
// Also writes the Pi output (folded-in k_pi). grid 16 x 256.
// ---------------------------------------------------------------------------
__global__ __launch_bounds__(256) void k_carry(
    const float* __restrict__ Aws, const float* __restrict__ Uws, float* __restrict__ Cws,
    const float* __restrict__ log_Pi, float* __restrict__ out)
{
    const int b = blockIdx.x >> 2;
    const int j = (blockIdx.x & 3) * 256 + threadIdx.x;
    if (blockIdx.x < 4) out[OUT_PI + j] = expf(log_Pi[j]);
    float carry = 0.0f;
    for (int c = 0; c < 64; ++c) {
        const size_t off = (size_t)(b * 64 + c) * 1024 + j;
        float a = Aws[off], u = Uws[off];
        Cws[off] = carry;               // carry entering chunk c
        carry = fmaf(a, carry, u);
    }
}

// ---------------------------------------------------------------------------
// K4: apply — rescan each 64-token chunk seeded with its carry.
// theta_hat = theta + d, overwriting the stashed u in place. grid 1024 x 256.
// ---------------------------------------------------------------------------
__global__ __launch_bounds__(256) void k_apply(
    const float* __restrict__ theta, const float* __restrict__ Cws, float* __restrict__ out)
{
    const int bid = blockIdx.x;          // (b<<8) | (c<<2) | jg
    const int jg = bid & 3;
    const int c  = (bid >> 2) & 63;
    const int b  = bid >> 8;
    const int j  = jg * 256 + threadIdx.x;
    float d = Cws[(size_t)(b * 64 + c) * 1024 + j];
    size_t idx = (size_t)(b * 4096 + c * 64) * 1024 + j;
    const float* __restrict__ Kbase = out + OUT_K;
#pragma unroll 4
    for (int i = 0; i < 64; ++i) {
        float Kg = Kbase[idx];
        float u  = out[idx];
        d = fmaf(1.0f - Kg, d, u);
        out[idx] = theta[idx] + d;
        idx += 1024;
    }
}

extern "C" void kernel_launch(void* const* d_in, const int* in_sizes, int n_in,
                              void* d_out, int out_size, void* d_ws, size_t ws_size,
                              hipStream_t stream)
{
    const float* theta = (const float*)d_in[0];
    const float* x     = (const float*)d_in[1];
    const float* logPi = (const float*)d_in[2];
    const float* Wr1   = (const float*)d_in[3];
    const float* br1   = (const float*)d_in[4];
    const float* Wr2   = (const float*)d_in[5];
    const float* br2   = (const float*)d_in[6];
    const float* Wm1   = (const float*)d_in[7];
    const float* bm1   = (const float*)d_in[8];
    const float* Wm2   = (const float*)d_in[9];
    const float* bm2   = (const float*)d_in[10];
    float* out = (float*)d_out;

    float* Hws = (float*)d_ws;                       // 16384*256 floats
    float* Aws = Hws + (size_t)16384 * 256;          // 262144 floats
    float* Uws = Aws + 262144;
    float* Cws = Uws + 262144;

    k_gemm1<<<dim3(512, 2), 256, 0, stream>>>(x, Wr1, br1, Wm1, bm1, Hws);
    k_head2<<<dim3(256, 16), 256, 0, stream>>>(Hws, Wr2, br2, Wm2, bm2, logPi, theta, out, Aws, Uws);
    k_carry<<<16, 256, 0, stream>>>(Aws, Uws, Cws, logPi, out);
    k_apply<<<1024, 256, 0, stream>>>(theta, Cws, out);
}

// Round 4
// 493.150 us; speedup vs baseline: 1.7258x; 1.2250x over previous
//
#include <hip/hip_runtime.h>
#include <math.h>

// B=4, L=4096, H=16, NB=64, D=1024, HID=128, NS=1024, TOKENS=16384
// Chunks: 64 tokens -> 64 chunks/seq, 256 chunks total.
// out layout: [theta_hat 16777216 | Pi 1024 | K 16777216 | R 16777216]
static constexpr size_t OUT_THETA = 0;
static constexpr size_t OUT_PI    = 16777216;
static constexpr size_t OUT_K     = 16778240;
static constexpr size_t OUT_R     = 33555456;

#define PI_F     3.14159265358979323846f
#define INV2PI_F 0.15915494309189535f
#define PI2_HI   6.28318548202514648f
#define PI2_LO  -1.7484556e-7f
#define SPLIT_S  2048.0f
#define SPLIT_IS (1.0f / 2048.0f)

typedef _Float16 half8 __attribute__((ext_vector_type(8)));
typedef float    f32x4 __attribute__((ext_vector_type(4)));

__device__ __forceinline__ float gelu_f(float x) {
    return 0.5f * x * (1.0f + erff(x * 0.70710678118654752f));
}

// ---------------------------------------------------------------------------
// k_prep: transpose + f16-split the four weight matrices (131072 els each).
// W1 (1024x128) -> [col][k] f16; W2 (128x1024) -> [col][k] f16.
// m-head weights get a scaled lo part: l = f16((w - h) * 2048).
// ---------------------------------------------------------------------------
__global__ __launch_bounds__(256) void k_prep(
    const float* __restrict__ Wr1, const float* __restrict__ Wm1,
    const float* __restrict__ Wr2, const float* __restrict__ Wm2,
    _Float16* __restrict__ W1rT, _Float16* __restrict__ W1mTh, _Float16* __restrict__ W1mTl,
    _Float16* __restrict__ W2rT, _Float16* __restrict__ W2mTh, _Float16* __restrict__ W2mTl)
{
    const int i = blockIdx.x * 256 + threadIdx.x;     // 0..131071
    { // W1: i = k*128 + c
        const int k = i >> 7, c = i & 127;
        const int o = c * 1024 + k;
        W1rT[o] = (_Float16)Wr1[i];
        float w = Wm1[i];
        _Float16 h = (_Float16)w;
        W1mTh[o] = h;
        W1mTl[o] = (_Float16)((w - (float)h) * SPLIT_S);
    }
    { // W2: i = k*1024 + c
        const int k = i >> 10, c = i & 1023;
        const int o = c * 128 + k;
        W2rT[o] = (_Float16)Wr2[i];
        float w = Wm2[i];
        _Float16 h = (_Float16)w;
        W2mTh[o] = h;
        W2mTl[o] = (_Float16)((w - (float)h) * SPLIT_S);
    }
}

// ---------------------------------------------------------------------------
// k_mm1<M>: H = gelu(X @ W1 + b1) for one head via MFMA 16x16x32 f16.
// M=false: r-head, single f16 product (error only feeds exp/divide chain).
// M=true : m-head, scaled f16x2: acc = A(h,h) + B(h,l + l,h)/2048  (~fp32).
// Block: 64 tokens x 128 cols, 4 waves (wave = 16-token row-tile).
// X is split fp32 -> f16 h + scaled-l on the fly during LDS staging.
// Outputs: M=false -> Hr f16; M=true -> Hmh f16, Hml = f16((g-h)*2048).
// ---------------------------------------------------------------------------
template<bool M>
__global__ __launch_bounds__(256, 3) void k_mm1(
    const float* __restrict__ X,
    const _Float16* __restrict__ WTh, const _Float16* __restrict__ WTl,
    const float* __restrict__ bias,
    _Float16* __restrict__ Oh, _Float16* __restrict__ Ol)
{
    __shared__ _Float16 sm[15360];
    _Float16* XH = sm;                 // [64][40]
    _Float16* XL = sm + 2560;          // [64][40]
    _Float16* WH = sm + 5120;          // [128][40]
    _Float16* WL = sm + 10240;         // [128][40]

    const int m0   = blockIdx.x * 64;
    const int tid  = threadIdx.x;
    const int lane = tid & 63;
    const int quad = lane >> 4, l15 = lane & 15;
    const int rt   = tid >> 6;                       // wave = row-tile
    const int arow = tid >> 2, aseg = tid & 3;       // X loader

    f32x4 accA[8] = {};
    f32x4 accB[8] = {};

    for (int k0 = 0; k0 < 1024; k0 += 32) {
        // global loads into regs
        const float* xp = X + (size_t)(m0 + arow) * 1024 + k0 + aseg * 8;
        float4 xa = *(const float4*)(xp);
        float4 xb = *(const float4*)(xp + 4);
        half8 wh[2], wl[2];
#pragma unroll
        for (int it = 0; it < 2; ++it) {
            const int u = tid + it * 256;            // 512 units: col 0..127, seg 0..3
            const int col = u >> 2, ws = u & 3;
            const size_t go = (size_t)col * 1024 + k0 + ws * 8;
            wh[it] = *(const half8*)(WTh + go);
            if (M) wl[it] = *(const half8*)(WTl + go);
        }
        __syncthreads();
        // stage X: convert to h + scaled l
        {
            half8 hh, hl;
#pragma unroll
            for (int c = 0; c < 8; ++c) {
                float v = (c < 4) ? ((const float*)&xa)[c] : ((const float*)&xb)[c - 4];
                _Float16 h = (_Float16)v;
                hh[c] = h;
                hl[c] = (_Float16)((v - (float)h) * SPLIT_S);
            }
            *(half8*)&XH[arow * 40 + aseg * 8] = hh;
            *(half8*)&XL[arow * 40 + aseg * 8] = hl;
        }
#pragma unroll
        for (int it = 0; it < 2; ++it) {
            const int u = tid + it * 256;
            const int col = u >> 2, ws = u & 3;
            *(half8*)&WH[col * 40 + ws * 8] = wh[it];
            if (M) *(half8*)&WL[col * 40 + ws * 8] = wl[it];
        }
        __syncthreads();
        // MFMA: one 16x16x32 covers the whole 32-k step
        half8 ah = *(const half8*)&XH[(rt * 16 + l15) * 40 + quad * 8];
        half8 al;
        if (M) al = *(const half8*)&XL[(rt * 16 + l15) * 40 + quad * 8];
#pragma unroll
        for (int ct = 0; ct < 8; ++ct) {
            half8 bh = *(const half8*)&WH[(ct * 16 + l15) * 40 + quad * 8];
            accA[ct] = __builtin_amdgcn_mfma_f32_16x16x32_f16(ah, bh, accA[ct], 0, 0, 0);
            if (M) {
                half8 bl = *(const half8*)&WL[(ct * 16 + l15) * 40 + quad * 8];
                accB[ct] = __builtin_amdgcn_mfma_f32_16x16x32_f16(ah, bl, accB[ct], 0, 0, 0);
                accB[ct] = __builtin_amdgcn_mfma_f32_16x16x32_f16(al, bh, accB[ct], 0, 0, 0);
            }
        }
    }
    // epilogue: bias + exact GELU; C/D layout col=lane&15, row=quad*4+reg
#pragma unroll
    for (int ct = 0; ct < 8; ++ct) {
        const int col = ct * 16 + l15;
        const float b = bias[col];
#pragma unroll
        for (int reg = 0; reg < 4; ++reg) {
            const int token = m0 + rt * 16 + quad * 4 + reg;
            float pre = accA[ct][reg] + (M ? accB[ct][reg] * SPLIT_IS : 0.0f) + b;
            float g = gelu_f(pre);
            const size_t o = (size_t)token * 128 + col;
            if (M) {
                _Float16 h = (_Float16)g;
                Oh[o] = h;
                Ol[o] = (_Float16)((g - (float)h) * SPLIT_S);
            } else {
                Oh[o] = (_Float16)g;
            }
        }
    }
}

// ---------------------------------------------------------------------------
// k_mm2: GEMM2 (both heads, K=128, MFMA) + elementwise tail + chunk aggregates.
// Block: 64 tokens (one chunk) x 64 cols, 4 waves; wave = 16-col tile x 4
// row-tiles. r-head: 1 MFMA/tile-step; m-head: 3 (scaled f16x2).
// Epilogue identical math to round 3; lane owns 4 consecutive tokens per
// (rt,quad) -> register affine fold, 16-segment LDS combine.
// ---------------------------------------------------------------------------
__global__ __launch_bounds__(256, 4) void k_mm2(
    const _Float16* __restrict__ Hr, const _Float16* __restrict__ Hmh, const _Float16* __restrict__ Hml,
    const _Float16* __restrict__ W2rT, const _Float16* __restrict__ W2mTh, const _Float16* __restrict__ W2mTl,
    const float* __restrict__ br2, const float* __restrict__ bm2,
    const float* __restrict__ log_Pi, const float* __restrict__ theta,
    float* __restrict__ out, float* __restrict__ Aws, float* __restrict__ Uws)
{
    __shared__ _Float16 sm[15360];
    _Float16* AHr = sm;                // [64][40]
    _Float16* AHm = sm + 2560;
    _Float16* ALm = sm + 5120;
    _Float16* BHr = sm + 7680;         // [64][40]
    _Float16* BHm = sm + 10240;
    _Float16* BLm = sm + 12800;

    const int tt = blockIdx.x;         // chunk 0..255
    const int jt = blockIdx.y;         // 0..15
    const int m0 = tt * 64, n0 = jt * 64;
    const int tid  = threadIdx.x;
    const int lane = tid & 63;
    const int quad = lane >> 4, l15 = lane & 15;
    const int ct   = tid >> 6;                       // wave = col-tile
    const int row  = tid >> 2, seg = tid & 3;        // loaders

    f32x4 accr[4] = {};
    f32x4 accA[4] = {};
    f32x4 accB[4] = {};

    for (int k0 = 0; k0 < 128; k0 += 32) {
        const size_t ao = (size_t)(m0 + row) * 128 + k0 + seg * 8;
        const size_t bo = (size_t)(n0 + row) * 128 + k0 + seg * 8;
        half8 la = *(const half8*)(Hr  + ao);
        half8 lb = *(const half8*)(Hmh + ao);
        half8 lc = *(const half8*)(Hml + ao);
        half8 ld = *(const half8*)(W2rT  + bo);
        half8 le = *(const half8*)(W2mTh + bo);
        half8 lf = *(const half8*)(W2mTl + bo);
        __syncthreads();
        const int so = row * 40 + seg * 8;
        *(half8*)&AHr[so] = la;
        *(half8*)&AHm[so] = lb;
        *(half8*)&ALm[so] = lc;
        *(half8*)&BHr[so] = ld;
        *(half8*)&BHm[so] = le;
        *(half8*)&BLm[so] = lf;
        __syncthreads();
        const int bidx = (ct * 16 + l15) * 40 + quad * 8;
        half8 br_ = *(const half8*)&BHr[bidx];
        half8 bm_ = *(const half8*)&BHm[bidx];
        half8 bl_ = *(const half8*)&BLm[bidx];
#pragma unroll
        for (int rt = 0; rt < 4; ++rt) {
            const int aidx = (rt * 16 + l15) * 40 + quad * 8;
            half8 a_r = *(const half8*)&AHr[aidx];
            half8 a_h = *(const half8*)&AHm[aidx];
            half8 a_l = *(const half8*)&ALm[aidx];
            accr[rt] = __builtin_amdgcn_mfma_f32_16x16x32_f16(a_r, br_, accr[rt], 0, 0, 0);
            accA[rt] = __builtin_amdgcn_mfma_f32_16x16x32_f16(a_h, bm_, accA[rt], 0, 0, 0);
            accB[rt] = __builtin_amdgcn_mfma_f32_16x16x32_f16(a_h, bl_, accB[rt], 0, 0, 0);
            accB[rt] = __builtin_amdgcn_mfma_f32_16x16x32_f16(a_l, bm_, accB[rt], 0, 0, 0);
        }
    }

    const int col = n0 + ct * 16 + l15;              // one column per lane
    const float Pi_  = expf(log_Pi[col]);
    const float b2rv = br2[col];
    const float b2mv = bm2[col];
    float segA[4], segU[4];
#pragma unroll
    for (int rt = 0; rt < 4; ++rt) {
        float A = 1.0f, U = 0.0f;
#pragma unroll
        for (int reg = 0; reg < 4; ++reg) {
            const int token = m0 + rt * 16 + quad * 4 + reg;
            const size_t idx = (size_t)token * 1024 + col;
            float lr = fminf(fmaxf(accr[rt][reg] + b2rv, -5.0f), 5.0f);
            float R  = expf(lr);
            float Kg = __fdividef(Pi_, fmaxf(Pi_ + R, 1e-8f));
            float zp = accA[rt][reg] + accB[rt][reg] * SPLIT_IS + b2mv;
            float z  = PI_F * tanhf(zp);
            float d  = z - theta[idx];
            float n  = rintf(d * INV2PI_F);
            float nu = fmaf(-n, PI2_HI, d);
            nu       = fmaf(-n, PI2_LO, nu);         // wrapped innovation
            float u  = Kg * nu;
            float al = 1.0f - Kg;
            U = fmaf(al, U, u);                      // token-ascending fold
            A *= al;
            out[OUT_K + idx]     = Kg;
            out[OUT_R + idx]     = R;
            out[OUT_THETA + idx] = u;                // u stashed in theta slot
        }
        segA[rt] = A; segU[rt] = U;
    }
    __syncthreads();                                 // MFMA LDS reads done; reuse
    float* cA = (float*)sm;                          // [64 cols][17 segs]
    float* cU = cA + 1088;
    const int colLocal = ct * 16 + l15;
#pragma unroll
    for (int rt = 0; rt < 4; ++rt) {
        cA[colLocal * 17 + rt * 4 + quad] = segA[rt];
        cU[colLocal * 17 + rt * 4 + quad] = segU[rt];
    }
    __syncthreads();
    if (tid < 64) {                                  // compose 16 segs in token order
        float A = 1.0f, U = 0.0f;
#pragma unroll
        for (int s = 0; s < 16; ++s) {
            float a = cA[tid * 17 + s];
            float u = cU[tid * 17 + s];
            U = fmaf(a, U, u);
            A *= a;
        }
        Aws[(size_t)tt * 1024 + n0 + tid] = A;
        Uws[(size_t)tt * 1024 + n0 + tid] = U;
    }
}

// ---------------------------------------------------------------------------
// K3: serial scan over 64 chunk aggregates per sequence -> chunk carries.
// Also writes Pi. grid 16 x 256.
// ---------------------------------------------------------------------------
__global__ __launch_bounds__(256) void k_carry(
    const float* __restrict__ Aws, const float* __restrict__ Uws, float* __restrict__ Cws,
    const float* __restrict__ log_Pi, float* __restrict__ out)
{
    const int b = blockIdx.x >> 2;
    const int j = (blockIdx.x & 3) * 256 + threadIdx.x;
    if (blockIdx.x < 4) out[OUT_PI + j] = expf(log_Pi[j]);
    float carry = 0.0f;
    for (int c = 0; c < 64; ++c) {
        const size_t off = (size_t)(b * 64 + c) * 1024 + j;
        float a = Aws[off], u = Uws[off];
        Cws[off] = carry;
        carry = fmaf(a, carry, u);
    }
}

// ---------------------------------------------------------------------------
// K4: apply — rescan each 64-token chunk seeded with its carry.
// theta_hat = theta + d, overwriting the stashed u in place. grid 1024 x 256.
// ---------------------------------------------------------------------------
__global__ __launch_bounds__(256) void k_apply(
    const float* __restrict__ theta, const float* __restrict__ Cws, float* __restrict__ out)
{
    const int bid = blockIdx.x;
    const int jg = bid & 3;
    const int c  = (bid >> 2) & 63;
    const int b  = bid >> 8;
    const int j  = jg * 256 + threadIdx.x;
    float d = Cws[(size_t)(b * 64 + c) * 1024 + j];
    size_t idx = (size_t)(b * 4096 + c * 64) * 1024 + j;
    const float* __restrict__ Kbase = out + OUT_K;
#pragma unroll 4
    for (int i = 0; i < 64; ++i) {
        float Kg = Kbase[idx];
        float u  = out[idx];
        d = fmaf(1.0f - Kg, d, u);
        out[idx] = theta[idx] + d;
        idx += 1024;
    }
}

extern "C" void kernel_launch(void* const* d_in, const int* in_sizes, int n_in,
                              void* d_out, int out_size, void* d_ws, size_t ws_size,
                              hipStream_t stream)
{
    const float* theta = (const float*)d_in[0];
    const float* x     = (const float*)d_in[1];
    const float* logPi = (const float*)d_in[2];
    const float* Wr1   = (const float*)d_in[3];
    const float* br1   = (const float*)d_in[4];
    const float* Wr2   = (const float*)d_in[5];
    const float* br2   = (const float*)d_in[6];
    const float* Wm1   = (const float*)d_in[7];
    const float* bm1   = (const float*)d_in[8];
    const float* Wm2   = (const float*)d_in[9];
    const float* bm2   = (const float*)d_in[10];
    float* out = (float*)d_out;

    // workspace carve (halfs first, then floats) — ~16.5 MB total
    _Float16* Hr    = (_Float16*)d_ws;                       // 16384*128
    _Float16* Hmh   = Hr  + (size_t)16384 * 128;
    _Float16* Hml   = Hmh + (size_t)16384 * 128;
    _Float16* W1rT  = Hml + (size_t)16384 * 128;             // 6 x 131072
    _Float16* W1mTh = W1rT  + 131072;
    _Float16* W1mTl = W1mTh + 131072;
    _Float16* W2rT  = W1mTl + 131072;
    _Float16* W2mTh = W2rT  + 131072;
    _Float16* W2mTl = W2mTh + 131072;
    float* Aws = (float*)(W2mTl + 131072);                   // 3 x 262144 f32
    float* Uws = Aws + 262144;
    float* Cws = Uws + 262144;

    k_prep<<<512, 256, 0, stream>>>(Wr1, Wm1, Wr2, Wm2,
                                    W1rT, W1mTh, W1mTl, W2rT, W2mTh, W2mTl);
    k_mm1<false><<<256, 256, 0, stream>>>(x, W1rT, nullptr, br1, Hr, nullptr);
    k_mm1<true ><<<256, 256, 0, stream>>>(x, W1mTh, W1mTl, bm1, Hmh, Hml);
    k_mm2<<<dim3(256, 16), 256, 0, stream>>>(Hr, Hmh, Hml, W2rT, W2mTh, W2mTl,
                                             br2, bm2, logPi, theta, out, Aws, Uws);
    k_carry<<<16, 256, 0, stream>>>(Aws, Uws, Cws, logPi, out);
    k_apply<<<1024, 256, 0, stream>>>(theta, Cws, out);
}